// Round 2
// baseline (413.584 us; speedup 1.0000x reference)
//
#include <hip/hip_runtime.h>

// Problem constants (from the reference): B=32, T=12, H=448, W=304.
constexpr int B  = 32;
constexpr int T  = 12;
constexpr int H  = 448;
constexpr int W  = 304;
constexpr int BT = B * T;                 // 384
constexpr int HW = H * W;                 // 136192 (divisible by 4)
constexpr int HW4 = HW / 4;               // 34048 float4s per (b,t) plane
constexpr long long TOTAL = (long long)BT * HW;   // 52,297,728
constexpr int N4 = BT * HW4;              // 13,074,432 float4s total
constexpr float SCALE_FACTOR = 1.0f;

constexpr int NTHREADS = 256;
constexpr int NBLOCKS  = 2048;            // ~8 blocks/CU; grid-stride covers the rest
constexpr int UNROLL   = 4;               // 12 loads in flight per thread

// Kernel 1: grid-stride partial reduction, unrolled x4 for memory-level
// parallelism. Each block writes ONE partial sum to d_ws (no atomics ->
// deterministic, no need to pre-zero poisoned d_ws).
__global__ __launch_bounds__(NTHREADS)
void wmse_partial(const float4* __restrict__ pred,
                  const float4* __restrict__ targ,
                  const int*    __restrict__ target_months,   // [BT], 1-based
                  const float*  __restrict__ monthly_weights, // [12]
                  const float4* __restrict__ area_w4,         // [HW4]
                  float* __restrict__ partials)               // [NBLOCKS]
{
    // Hoist the per-(b,t) month-weight gather into LDS once per block.
    __shared__ float mw[BT];
    for (int i = threadIdx.x; i < BT; i += blockDim.x)
        mw[i] = monthly_weights[target_months[i] - 1];
    __syncthreads();

    const int stride = gridDim.x * blockDim.x;
    int i = blockIdx.x * blockDim.x + threadIdx.x;

    float acc0 = 0.0f, acc1 = 0.0f, acc2 = 0.0f, acc3 = 0.0f;

    // Unrolled main loop: 4 independent {pred,targ,area} triples in flight.
    for (; i + 3 * stride < N4; i += UNROLL * stride) {
        const int i0 = i, i1 = i + stride, i2 = i + 2 * stride, i3 = i + 3 * stride;

        float4 p0 = pred[i0], p1 = pred[i1], p2 = pred[i2], p3 = pred[i3];
        float4 t0 = targ[i0], t1 = targ[i1], t2 = targ[i2], t3 = targ[i3];

        const int bt0 = i0 / HW4, bt1 = i1 / HW4, bt2 = i2 / HW4, bt3 = i3 / HW4;
        float4 a0 = area_w4[i0 - bt0 * HW4];
        float4 a1 = area_w4[i1 - bt1 * HW4];
        float4 a2 = area_w4[i2 - bt2 * HW4];
        float4 a3 = area_w4[i3 - bt3 * HW4];

        const float w0 = mw[bt0], w1 = mw[bt1], w2 = mw[bt2], w3 = mw[bt3];

        float d;
        d = (t0.x - p0.x) * w0 * a0.x; acc0 += d * d;
        d = (t0.y - p0.y) * w0 * a0.y; acc0 += d * d;
        d = (t0.z - p0.z) * w0 * a0.z; acc0 += d * d;
        d = (t0.w - p0.w) * w0 * a0.w; acc0 += d * d;

        d = (t1.x - p1.x) * w1 * a1.x; acc1 += d * d;
        d = (t1.y - p1.y) * w1 * a1.y; acc1 += d * d;
        d = (t1.z - p1.z) * w1 * a1.z; acc1 += d * d;
        d = (t1.w - p1.w) * w1 * a1.w; acc1 += d * d;

        d = (t2.x - p2.x) * w2 * a2.x; acc2 += d * d;
        d = (t2.y - p2.y) * w2 * a2.y; acc2 += d * d;
        d = (t2.z - p2.z) * w2 * a2.z; acc2 += d * d;
        d = (t2.w - p2.w) * w2 * a2.w; acc2 += d * d;

        d = (t3.x - p3.x) * w3 * a3.x; acc3 += d * d;
        d = (t3.y - p3.y) * w3 * a3.y; acc3 += d * d;
        d = (t3.z - p3.z) * w3 * a3.z; acc3 += d * d;
        d = (t3.w - p3.w) * w3 * a3.w; acc3 += d * d;
    }

    // Remainder.
    for (; i < N4; i += stride) {
        const int bt = i / HW4;
        float4 p = pred[i];
        float4 t = targ[i];
        float4 a = area_w4[i - bt * HW4];
        const float w = mw[bt];
        float d;
        d = (t.x - p.x) * w * a.x; acc0 += d * d;
        d = (t.y - p.y) * w * a.y; acc0 += d * d;
        d = (t.z - p.z) * w * a.z; acc0 += d * d;
        d = (t.w - p.w) * w * a.w; acc0 += d * d;
    }

    float acc = (acc0 + acc1) + (acc2 + acc3);

    // Wave-64 butterfly reduce, then cross-wave via LDS.
    #pragma unroll
    for (int off = 32; off > 0; off >>= 1)
        acc += __shfl_down(acc, off);

    __shared__ float wsum[NTHREADS / 64];
    const int lane = threadIdx.x & 63;
    const int wid  = threadIdx.x >> 6;
    if (lane == 0) wsum[wid] = acc;
    __syncthreads();
    if (threadIdx.x == 0) {
        float s = 0.0f;
        #pragma unroll
        for (int w2 = 0; w2 < NTHREADS / 64; ++w2) s += wsum[w2];
        partials[blockIdx.x] = s;
    }
}

// Kernel 2: one block folds the NBLOCKS partials and writes the mean.
__global__ __launch_bounds__(NTHREADS)
void wmse_final(const float* __restrict__ partials, float* __restrict__ out)
{
    float acc = 0.0f;
    for (int i = threadIdx.x; i < NBLOCKS; i += blockDim.x)
        acc += partials[i];

    #pragma unroll
    for (int off = 32; off > 0; off >>= 1)
        acc += __shfl_down(acc, off);

    __shared__ float wsum[NTHREADS / 64];
    const int lane = threadIdx.x & 63;
    const int wid  = threadIdx.x >> 6;
    if (lane == 0) wsum[wid] = acc;
    __syncthreads();
    if (threadIdx.x == 0) {
        float s = 0.0f;
        #pragma unroll
        for (int w2 = 0; w2 < NTHREADS / 64; ++w2) s += wsum[w2];
        out[0] = s * (SCALE_FACTOR / (float)TOTAL);
    }
}

extern "C" void kernel_launch(void* const* d_in, const int* in_sizes, int n_in,
                              void* d_out, int out_size, void* d_ws, size_t ws_size,
                              hipStream_t stream) {
    const float4* pred = (const float4*)d_in[0];
    const float4* targ = (const float4*)d_in[1];
    const int*    tm   = (const int*)d_in[2];
    const float*  mw   = (const float*)d_in[3];
    const float4* aw   = (const float4*)d_in[4];
    float* out = (float*)d_out;
    float* partials = (float*)d_ws;   // NBLOCKS * 4 bytes, rewritten every call

    wmse_partial<<<NBLOCKS, NTHREADS, 0, stream>>>(pred, targ, tm, mw, aw, partials);
    wmse_final<<<1, NTHREADS, 0, stream>>>(partials, out);
}

// Round 3
// 411.762 us; speedup vs baseline: 1.0044x; 1.0044x over previous
//
#include <hip/hip_runtime.h>

// Problem constants (from the reference): B=32, T=12, H=448, W=304.
constexpr int B  = 32;
constexpr int T  = 12;
constexpr int H  = 448;
constexpr int W  = 304;
constexpr int BT = B * T;                 // 384 planes
constexpr int HW = H * W;                 // 136192 (divisible by 4)
constexpr int HW4 = HW / 4;               // 34048 float4s per (b,t) plane
constexpr long long TOTAL = (long long)BT * HW;   // 52,297,728
constexpr float SCALE_FACTOR = 1.0f;

constexpr int NTHREADS = 256;
constexpr int PLANES_PER_GROUP = 24;      // 384 = 16 * 24, unrolled 4 -> 6 iters
constexpr int NGROUPS = BT / PLANES_PER_GROUP;   // 16
constexpr int CHUNKS  = HW4 / NTHREADS;   // 34048 / 256 = 133 exactly
constexpr int NBLOCKS = CHUNKS * NGROUPS; // 2128

// Each block owns ONE 256-float4 spatial chunk and 24 consecutive planes.
// area weights for the chunk live in registers (a^2), so the inner loop is a
// pure 2-stream read: pred + targ, 8 independent dwordx4 loads per step.
__global__ __launch_bounds__(NTHREADS)
void wmse_partial(const float4* __restrict__ pred,
                  const float4* __restrict__ targ,
                  const int*    __restrict__ target_months,   // [BT], 1-based
                  const float*  __restrict__ monthly_weights, // [12]
                  const float4* __restrict__ area_w4,         // [HW4]
                  float* __restrict__ partials)               // [NBLOCKS]
{
    const int tid   = threadIdx.x;
    const int chunk = blockIdx.x % CHUNKS;     // fast-varying -> contiguous sweep
    const int group = blockIdx.x / CHUNKS;
    const int plane0 = group * PLANES_PER_GROUP;
    const int sp = chunk * NTHREADS + tid;     // spatial float4 index

    // Fold month weight as w^2; stage the block's 24 plane weights in LDS.
    __shared__ float w2s[PLANES_PER_GROUP];
    if (tid < PLANES_PER_GROUP) {
        float w = monthly_weights[target_months[plane0 + tid] - 1];
        w2s[tid] = w * w;
    }

    // Per-thread area^2 in registers (removes the third global stream).
    float4 a = area_w4[sp];
    const float a2x = a.x * a.x, a2y = a.y * a.y, a2z = a.z * a.z, a2w = a.w * a.w;
    __syncthreads();

    const float4* __restrict__ p = pred + (size_t)plane0 * HW4 + sp;
    const float4* __restrict__ t = targ + (size_t)plane0 * HW4 + sp;

    float accA = 0.0f, accB = 0.0f;

    #pragma unroll 1
    for (int k = 0; k < PLANES_PER_GROUP; k += 4) {
        // 8 independent loads in flight before any use.
        float4 p0 = p[0];
        float4 p1 = p[HW4];
        float4 p2 = p[2 * HW4];
        float4 p3 = p[3 * HW4];
        float4 t0 = t[0];
        float4 t1 = t[HW4];
        float4 t2 = t[2 * HW4];
        float4 t3 = t[3 * HW4];

        float d, s0 = 0.f, s1 = 0.f, s2 = 0.f, s3 = 0.f;
        d = t0.x - p0.x; s0 = fmaf(a2x * d, d, s0);
        d = t0.y - p0.y; s0 = fmaf(a2y * d, d, s0);
        d = t0.z - p0.z; s0 = fmaf(a2z * d, d, s0);
        d = t0.w - p0.w; s0 = fmaf(a2w * d, d, s0);

        d = t1.x - p1.x; s1 = fmaf(a2x * d, d, s1);
        d = t1.y - p1.y; s1 = fmaf(a2y * d, d, s1);
        d = t1.z - p1.z; s1 = fmaf(a2z * d, d, s1);
        d = t1.w - p1.w; s1 = fmaf(a2w * d, d, s1);

        d = t2.x - p2.x; s2 = fmaf(a2x * d, d, s2);
        d = t2.y - p2.y; s2 = fmaf(a2y * d, d, s2);
        d = t2.z - p2.z; s2 = fmaf(a2z * d, d, s2);
        d = t2.w - p2.w; s2 = fmaf(a2w * d, d, s2);

        d = t3.x - p3.x; s3 = fmaf(a2x * d, d, s3);
        d = t3.y - p3.y; s3 = fmaf(a2y * d, d, s3);
        d = t3.z - p3.z; s3 = fmaf(a2z * d, d, s3);
        d = t3.w - p3.w; s3 = fmaf(a2w * d, d, s3);

        // w2s reads are at compile-time offsets within the unrolled step:
        // uniform-address LDS broadcast, conflict-free.
        accA = fmaf(w2s[k],     s0, accA);
        accB = fmaf(w2s[k + 1], s1, accB);
        accA = fmaf(w2s[k + 2], s2, accA);
        accB = fmaf(w2s[k + 3], s3, accB);

        p += 4 * HW4;
        t += 4 * HW4;
    }

    float acc = accA + accB;

    // Wave-64 reduce, then cross-wave via LDS.
    #pragma unroll
    for (int off = 32; off > 0; off >>= 1)
        acc += __shfl_down(acc, off);

    __shared__ float wsum[NTHREADS / 64];
    const int lane = tid & 63;
    const int wid  = tid >> 6;
    if (lane == 0) wsum[wid] = acc;
    __syncthreads();
    if (tid == 0) {
        float s = 0.0f;
        #pragma unroll
        for (int w2 = 0; w2 < NTHREADS / 64; ++w2) s += wsum[w2];
        partials[blockIdx.x] = s;
    }
}

// One block folds the NBLOCKS partials and writes the mean.
__global__ __launch_bounds__(NTHREADS)
void wmse_final(const float* __restrict__ partials, float* __restrict__ out)
{
    float acc = 0.0f;
    for (int i = threadIdx.x; i < NBLOCKS; i += blockDim.x)
        acc += partials[i];

    #pragma unroll
    for (int off = 32; off > 0; off >>= 1)
        acc += __shfl_down(acc, off);

    __shared__ float wsum[NTHREADS / 64];
    const int lane = threadIdx.x & 63;
    const int wid  = threadIdx.x >> 6;
    if (lane == 0) wsum[wid] = acc;
    __syncthreads();
    if (threadIdx.x == 0) {
        float s = 0.0f;
        #pragma unroll
        for (int w2 = 0; w2 < NTHREADS / 64; ++w2) s += wsum[w2];
        out[0] = s * (SCALE_FACTOR / (float)TOTAL);
    }
}

extern "C" void kernel_launch(void* const* d_in, const int* in_sizes, int n_in,
                              void* d_out, int out_size, void* d_ws, size_t ws_size,
                              hipStream_t stream) {
    const float4* pred = (const float4*)d_in[0];
    const float4* targ = (const float4*)d_in[1];
    const int*    tm   = (const int*)d_in[2];
    const float*  mw   = (const float*)d_in[3];
    const float4* aw   = (const float4*)d_in[4];
    float* out = (float*)d_out;
    float* partials = (float*)d_ws;   // NBLOCKS * 4 bytes, rewritten every call

    wmse_partial<<<NBLOCKS, NTHREADS, 0, stream>>>(pred, targ, tm, mw, aw, partials);
    wmse_final<<<1, NTHREADS, 0, stream>>>(partials, out);
}